// Round 1
// baseline (98.245 us; speedup 1.0000x reference)
//
#include <hip/hip_runtime.h>
#include <hip/hip_bf16.h>
#include <cmath>

#define HW 262144          // 512*512
#define NC 16
#define NB 8
#define NSEG 16
#define SEGSZ (HW / NSEG)  // 16384
#define EPS 1e-5f

// ---------------- pass 1: per-(b,c,seg) partial sum & max ----------------
__global__ __launch_bounds__(256) void k_reduce(const float* __restrict__ x,
                                                float* __restrict__ psum,
                                                float* __restrict__ pmax) {
    int plane = blockIdx.x / NSEG;
    int seg   = blockIdx.x - plane * NSEG;
    const float4* p = reinterpret_cast<const float4*>(
        x + (size_t)plane * HW + (size_t)seg * SEGSZ);
    int t = threadIdx.x;
    float s = 0.0f, m = -INFINITY;
    #pragma unroll
    for (int it = 0; it < SEGSZ / (256 * 4); ++it) {
        float4 v = p[it * 256 + t];
        s += (v.x + v.y) + (v.z + v.w);
        m = fmaxf(m, fmaxf(fmaxf(v.x, v.y), fmaxf(v.z, v.w)));
    }
    #pragma unroll
    for (int off = 32; off > 0; off >>= 1) {
        s += __shfl_down(s, off, 64);
        m = fmaxf(m, __shfl_down(m, off, 64));
    }
    __shared__ float ls[4], lm[4];
    int wid = t >> 6, lane = t & 63;
    if (lane == 0) { ls[wid] = s; lm[wid] = m; }
    __syncthreads();
    if (t == 0) {
        psum[blockIdx.x] = (ls[0] + ls[1]) + (ls[2] + ls[3]);
        pmax[blockIdx.x] = fmaxf(fmaxf(lm[0], lm[1]), fmaxf(lm[2], lm[3]));
    }
}

// ---------------- pass 2: fold per-batch matrices ----------------
// params layout per batch (816 floats):
// [0:256)   A_T   (A[o][i] stored at i*16+o)
// [256:272) abias
// [272:528) G_T
// [528:544) gbias
// [544:800) W4_T
// [800:816) b4
__global__ __launch_bounds__(256) void k_params(
    const float* __restrict__ psum, const float* __restrict__ pmax,
    const float* __restrict__ Wc, const float* __restrict__ bc,
    const float* __restrict__ W1, const float* __restrict__ b1,
    const float* __restrict__ W2, const float* __restrict__ b2,
    const float* __restrict__ W3, const float* __restrict__ b3,
    const float* __restrict__ W4, const float* __restrict__ b4,
    float* __restrict__ params) {
    int b = blockIdx.x;
    int t = threadIdx.x;
    __shared__ float r2[NC], r4[NC], sWc[256], sW1[256], sW2[256], sW3[256];
    if (t < NC) {
        float s = 0.0f, m = -INFINITY;
        for (int k = 0; k < NSEG; ++k) {
            s += psum[(b * NC + t) * NSEG + k];
            m = fmaxf(m, pmax[(b * NC + t) * NSEG + k]);
        }
        r2[t] = 1.0f / (s * (1.0f / (float)HW) + EPS);
        r4[t] = 1.0f / (m + EPS);
    }
    sWc[t] = Wc[t]; sW1[t] = W1[t]; sW2[t] = W2[t]; sW3[t] = W3[t];
    __syncthreads();
    int o = t >> 4, i = t & 15;
    float accA = 0.0f, accG = 0.0f;
    #pragma unroll
    for (int c = 0; c < NC; ++c) {
        accA += sW2[o * NC + c] * r2[c] * sWc[c * NC + i];
        accG += sW3[o * NC + c] * r4[c] * sW1[c * NC + i];
    }
    float* P = params + b * 816;
    P[i * NC + o]       = accA;
    P[272 + i * NC + o] = accG;
    P[544 + i * NC + o] = W4[o * NC + i];
    if (i == 0) {
        float ba = 0.0f, bg = 0.0f;
        #pragma unroll
        for (int c = 0; c < NC; ++c) {
            ba += sW2[o * NC + c] * r2[c] * bc[c];
            bg += sW3[o * NC + c] * r4[c] * b1[c];
        }
        P[256 + o] = ba + b2[o];
        P[528 + o] = bg + b3[o];
        P[800 + o] = b4[o];
    }
}

// sigmoid(tanh(x)): tanh via fast exp+rcp (saturates correctly at +-inf),
// sigmoid via odd Taylor on [-1,1] (max abs err ~2e-4)
__device__ __forceinline__ float gsig(float x) {
    float E = __expf(2.0f * x);
    float t = 1.0f - 2.0f * __builtin_amdgcn_rcpf(E + 1.0f);   // tanh(x)
    float t2 = t * t;
    return fmaf(t, fmaf(t2, fmaf(t2, 0.0020833333f, -0.0208333333f), 0.25f), 0.5f);
}

// ---------------- pass 3: fused per-pixel ----------------
__global__ __launch_bounds__(256) void k_main(const float* __restrict__ x,
                                              const float* __restrict__ params,
                                              float* __restrict__ out) {
    int b = blockIdx.x >> 9;            // 512 blocks per batch
    int j = blockIdx.x & 511;
    int p = j * 512 + threadIdx.x * 2;  // 2 pixels per thread
    const float* __restrict__ P = params + b * 816;   // block-uniform -> s_load
    const float* xb = x + (size_t)b * NC * HW + p;
    float* ob = out + (size_t)b * NC * HW + p;

    float2 v[NC];
    #pragma unroll
    for (int c = 0; c < NC; ++c)
        v[c] = *reinterpret_cast<const float2*>(xb + (size_t)c * HW);

    float2 wh[NC], gr[NC];
    #pragma unroll
    for (int o = 0; o < NC; ++o) {
        float ab = P[256 + o], gb = P[528 + o];
        wh[o] = make_float2(ab, ab);
        gr[o] = make_float2(gb, gb);
    }
    #pragma unroll
    for (int i = 0; i < NC; ++i) {
        float vx = v[i].x, vy = v[i].y;
        #pragma unroll
        for (int o = 0; o < NC; ++o) {
            float a = P[i * NC + o];
            float g = P[272 + i * NC + o];
            wh[o].x = fmaf(a, vx, wh[o].x); wh[o].y = fmaf(a, vy, wh[o].y);
            gr[o].x = fmaf(g, vx, gr[o].x); gr[o].y = fmaf(g, vy, gr[o].y);
        }
    }
    #pragma unroll
    for (int o = 0; o < NC; ++o) {
        float wx = 1.0f + gsig(wh[o].x) + gsig(gr[o].x);
        float wy = 1.0f + gsig(wh[o].y) + gsig(gr[o].y);
        v[o].x *= wx; v[o].y *= wy;
    }
    float2 acc[NC];
    #pragma unroll
    for (int o = 0; o < NC; ++o) {
        float bb = P[800 + o];
        acc[o] = make_float2(bb, bb);
    }
    #pragma unroll
    for (int i = 0; i < NC; ++i) {
        float vx = v[i].x, vy = v[i].y;
        #pragma unroll
        for (int o = 0; o < NC; ++o) {
            float wv = P[544 + i * NC + o];
            acc[o].x = fmaf(wv, vx, acc[o].x); acc[o].y = fmaf(wv, vy, acc[o].y);
        }
    }
    #pragma unroll
    for (int o = 0; o < NC; ++o)
        *reinterpret_cast<float2*>(ob + (size_t)o * HW) = acc[o];
}

extern "C" void kernel_launch(void* const* d_in, const int* in_sizes, int n_in,
                              void* d_out, int out_size, void* d_ws, size_t ws_size,
                              hipStream_t stream) {
    const float* x  = (const float*)d_in[0];
    const float* Wc = (const float*)d_in[1];
    const float* bc = (const float*)d_in[2];
    const float* W1 = (const float*)d_in[3];
    const float* b1 = (const float*)d_in[4];
    const float* W2 = (const float*)d_in[5];
    const float* b2 = (const float*)d_in[6];
    const float* W3 = (const float*)d_in[7];
    const float* b3 = (const float*)d_in[8];
    const float* W4 = (const float*)d_in[9];
    const float* b4 = (const float*)d_in[10];
    float* out = (float*)d_out;

    float* psum   = (float*)d_ws;                 // 128*16 floats
    float* pmax   = psum + NB * NC * NSEG;        // 128*16 floats
    float* params = pmax + NB * NC * NSEG;        // 8*816 floats

    k_reduce<<<NB * NC * NSEG, 256, 0, stream>>>(x, psum, pmax);
    k_params<<<NB, 256, 0, stream>>>(psum, pmax, Wc, bc, W1, b1, W2, b2,
                                     W3, b3, W4, b4, params);
    k_main<<<NB * 512, 256, 0, stream>>>(x, params, out);
}